// Round 3
// baseline (1021.700 us; speedup 1.0000x reference)
//
#include <hip/hip_runtime.h>
#include <math.h>

#define BN_EPS 1e-5f

// ---------------------------------------------------------------------------
// Weight transpose: w[co][ci][kh][kw] -> wt[ci][kpos][co]
// so that for fixed (ci,kpos) the 8 per-co weights are contiguous (s_load).
// ---------------------------------------------------------------------------
__global__ void wtrans_kernel(const float* __restrict__ w, float* __restrict__ wt) {
    int i = blockIdx.x * 256 + threadIdx.x;
    if (i >= 128 * 128 * 9) return;
    int co = i / 1152;
    int rem = i - co * 1152;
    int ci = rem / 9;
    int kpos = rem - ci * 9;
    wt[ci * 1152 + kpos * 128 + co] = w[i];
}

// ---------------------------------------------------------------------------
// AdderNet conv (3x3, pad 1), PARTIAL over half the ci range.
// Grid: (4 row-tiles, 16 co-blocks of 8, 32 = 16 n x 2 ci-halves)
//       = 2048 blocks -> 8 blocks/CU -> 32 waves/CU.
// Block: 256 threads, 1 output pixel/thread, 8 output channels/thread.
// 4 ci planes staged per barrier (double-buffered, 10.9KB LDS).
// Writes acc (positive sum of |x-w|) to dst0 (half 0) or dst1 (half 1).
// ---------------------------------------------------------------------------
__global__ __launch_bounds__(256, 8) void adder_conv_part(
    const float* __restrict__ src,   // [16,128,32,32]
    const float* __restrict__ wt,    // [ci][9][co] transposed weights
    float* __restrict__ dst0, float* __restrict__ dst1) {
    const int t = threadIdx.x;
    const int r = t >> 5;                 // 0..7 row within tile
    const int c = t & 31;                 // 0..31 col
    const int row0 = blockIdx.x * 8;      // tile start row
    const int cb = blockIdx.y;            // co base = cb*8
    const int n = blockIdx.z & 15;
    const int half = blockIdx.z >> 4;     // ci half: 0 or 1
    const int cibase = half * 64;

    __shared__ float lds[2][4][340];      // 4 ci planes x (10x34), double-buffered

    // Staging geometry: element e -> (lr, lc) in padded tile, global offset.
    const int e0 = t;
    const int lr0 = e0 / 34, lc0 = e0 - lr0 * 34;
    const int gr0 = row0 + lr0 - 1, gc0 = lc0 - 1;
    const bool ok0 = (gr0 >= 0 && gr0 < 32 && gc0 >= 0 && gc0 < 32);
    const int off0 = gr0 * 32 + gc0;

    const int e1 = t + 256;
    const int lr1 = e1 / 34, lc1 = e1 - lr1 * 34;
    const int gr1 = row0 + lr1 - 1, gc1 = lc1 - 1;
    const bool st1 = (e1 < 340);
    const bool ok1 = st1 && (gr1 >= 0 && gr1 < 32 && gc1 >= 0 && gc1 < 32);
    const int off1 = gr1 * 32 + gc1;

    const float* splane = src + (size_t)n * (128 * 1024) + cibase * 1024;

    float acc[8];
#pragma unroll
    for (int j = 0; j < 8; ++j) acc[j] = 0.f;

    // Prologue: stage group 0 (4 planes) into buffer 0.
#pragma unroll
    for (int p = 0; p < 4; ++p) {
        const float* sp = splane + p * 1024;
        lds[0][p][e0] = ok0 ? sp[off0] : 0.f;
        if (st1) lds[0][p][e1] = ok1 ? sp[off1] : 0.f;
    }
    __syncthreads();

    const int base = r * 34 + c;
    int cur = 0;

    for (int g = 0; g < 16; ++g) {
        // Prefetch next group of 4 ci planes into registers (overlaps compute).
        float pf0[4], pf1[4];
        const bool more = (g < 15);
        if (more) {
#pragma unroll
            for (int p = 0; p < 4; ++p) {
                const float* sp = splane + ((g + 1) * 4 + p) * 1024;
                pf0[p] = ok0 ? sp[off0] : 0.f;
                pf1[p] = ok1 ? sp[off1] : 0.f;
            }
        }
        // Compute 4 ci planes.
#pragma unroll
        for (int p = 0; p < 4; ++p) {
            const int ci = cibase + g * 4 + p;
            const float* wrow = wt + ci * 1152 + cb * 8;   // wave-uniform
#pragma unroll
            for (int kh = 0; kh < 3; ++kh) {
#pragma unroll
                for (int kw = 0; kw < 3; ++kw) {
                    const float xv = lds[cur][p][base + kh * 34 + kw];
                    const float* wp = wrow + (kh * 3 + kw) * 128;
#pragma unroll
                    for (int j = 0; j < 8; ++j)
                        acc[j] += fabsf(xv - wp[j]);
                }
            }
        }
        if (more) {
#pragma unroll
            for (int p = 0; p < 4; ++p) {
                lds[cur ^ 1][p][e0] = pf0[p];
                if (st1) lds[cur ^ 1][p][e1] = pf1[p];
            }
        }
        __syncthreads();
        cur ^= 1;
    }

    // Epilogue: store positive partial sums, coalesced.
    float* dst = half ? dst1 : dst0;
#pragma unroll
    for (int j = 0; j < 8; ++j) {
        const int co = cb * 8 + j;
        dst[(((size_t)n * 128 + co) * 32 + (row0 + r)) * 32 + c] = acc[j];
    }
}

// ---------------------------------------------------------------------------
// Combine: out = BN(-(pA+pB)) (+ReLU). out may alias pA. float4 vectorized.
// ---------------------------------------------------------------------------
template <bool RELU>
__global__ void combine_bn(const float* pA, const float* pB,
                           const float* __restrict__ gamma, const float* __restrict__ beta,
                           const float* __restrict__ mean, const float* __restrict__ var,
                           float* out) {
    const int i = blockIdx.x * 256 + threadIdx.x;   // float4 index, 524288 total
    const int co = (i >> 8) & 127;                   // 256 float4 per (n,c)
    const float iv = gamma[co] * rsqrtf(var[co] + BN_EPS);
    const float bb = beta[co] - mean[co] * iv;
    const float4 a = ((const float4*)pA)[i];
    const float4 b = ((const float4*)pB)[i];
    float4 o;
    o.x = bb - (a.x + b.x) * iv;
    o.y = bb - (a.y + b.y) * iv;
    o.z = bb - (a.z + b.z) * iv;
    o.w = bb - (a.w + b.w) * iv;
    if (RELU) {
        o.x = fmaxf(o.x, 0.f); o.y = fmaxf(o.y, 0.f);
        o.z = fmaxf(o.z, 0.f); o.w = fmaxf(o.w, 0.f);
    }
    ((float4*)out)[i] = o;
}

// ---------------------------------------------------------------------------
// Per-(n,c) spatial mean of z: [16,128,32,32] -> [16,128]
// ---------------------------------------------------------------------------
__global__ void mean_kernel(const float* __restrict__ z, float* __restrict__ means) {
    const int b = blockIdx.x;  // n*128 + c
    const float4 v = ((const float4*)(z + (size_t)b * 1024))[threadIdx.x];
    float sum = v.x + v.y + v.z + v.w;
#pragma unroll
    for (int o = 32; o > 0; o >>= 1) sum += __shfl_down(sum, o);
    __shared__ float ws_[4];
    if ((threadIdx.x & 63) == 0) ws_[threadIdx.x >> 6] = sum;
    __syncthreads();
    if (threadIdx.x == 0)
        means[b] = (ws_[0] + ws_[1] + ws_[2] + ws_[3]) * (1.f / 1024.f);
}

// ---------------------------------------------------------------------------
// SE gate: s = sigmoid(fc2(relu(fc1(mean)+b1))+b2), per image n.
// ---------------------------------------------------------------------------
__global__ void se_kernel(const float* __restrict__ means,
                          const float* __restrict__ fc1w, const float* __restrict__ fc1b,
                          const float* __restrict__ fc2w, const float* __restrict__ fc2b,
                          float* __restrict__ s) {
    const int n = blockIdx.x;     // 16 blocks, 128 threads
    const int t = threadIdx.x;
    __shared__ float m[128], rr[8];
    m[t] = means[n * 128 + t];
    __syncthreads();
    if (t < 8) {
        float a = fc1b[t];
        for (int c2 = 0; c2 < 128; ++c2) a += fc1w[t * 128 + c2] * m[c2];
        rr[t] = fmaxf(a, 0.f);
    }
    __syncthreads();
    float a = fc2b[t];
#pragma unroll
    for (int j = 0; j < 8; ++j) a += fc2w[t * 8 + j] * rr[j];
    s[n * 128 + t] = 1.f / (1.f + expf(-a));
}

// ---------------------------------------------------------------------------
// Final: out = relu(z * s[n,c] + x), vectorized float4.
// ---------------------------------------------------------------------------
__global__ void final_kernel(const float* __restrict__ z, const float* __restrict__ x,
                             const float* __restrict__ s, float* __restrict__ out) {
    const int i = blockIdx.x * 256 + threadIdx.x;   // float4 index, 524288 total
    const int plane = i >> 8;                        // 256 float4 per (n,c)
    const float sc = s[plane];
    const float4 zv = ((const float4*)z)[i];
    const float4 xv = ((const float4*)x)[i];
    float4 o;
    o.x = fmaxf(zv.x * sc + xv.x, 0.f);
    o.y = fmaxf(zv.y * sc + xv.y, 0.f);
    o.z = fmaxf(zv.z * sc + xv.z, 0.f);
    o.w = fmaxf(zv.w * sc + xv.w, 0.f);
    ((float4*)out)[i] = o;
}

// ---------------------------------------------------------------------------
extern "C" void kernel_launch(void* const* d_in, const int* in_sizes, int n_in,
                              void* d_out, int out_size, void* d_ws, size_t ws_size,
                              hipStream_t stream) {
    const float* x    = (const float*)d_in[0];
    const float* w1   = (const float*)d_in[1];
    const float* g1   = (const float*)d_in[2];
    const float* b1   = (const float*)d_in[3];
    const float* m1   = (const float*)d_in[4];
    const float* v1   = (const float*)d_in[5];
    const float* w2   = (const float*)d_in[6];
    const float* g2   = (const float*)d_in[7];
    const float* b2   = (const float*)d_in[8];
    const float* m2   = (const float*)d_in[9];
    const float* v2   = (const float*)d_in[10];
    const float* fc1w = (const float*)d_in[11];
    const float* fc1b = (const float*)d_in[12];
    const float* fc2w = (const float*)d_in[13];
    const float* fc2b = (const float*)d_in[14];
    float* out = (float*)d_out;

    float* ws    = (float*)d_ws;
    float* wt1   = ws;                   // 147456
    float* wt2   = wt1 + 147456;         // 147456
    float* pA    = wt2 + 147456;         // 2097152
    float* pB    = pA + 2097152;         // 2097152
    float* z     = pB + 2097152;         // 2097152
    float* means = z + 2097152;          // 2048
    float* s     = means + 2048;         // 2048

    wtrans_kernel<<<576, 256, 0, stream>>>(w1, wt1);
    wtrans_kernel<<<576, 256, 0, stream>>>(w2, wt2);

    dim3 cgrid(4, 16, 32);
    // Conv1 partials -> pA (half0), pB (half1); combine -> y lives in pA.
    adder_conv_part<<<cgrid, 256, 0, stream>>>(x, wt1, pA, pB);
    combine_bn<true ><<<2048, 256, 0, stream>>>(pA, pB, g1, b1, m1, v1, pA);
    // Conv2 partials (src = y = pA) -> pB (half0), z (half1); combine -> z.
    adder_conv_part<<<cgrid, 256, 0, stream>>>(pA, wt2, pB, z);
    combine_bn<false><<<2048, 256, 0, stream>>>(pB, z, g2, b2, m2, v2, z);

    mean_kernel<<<2048, 256, 0, stream>>>(z, means);
    se_kernel<<<16, 128, 0, stream>>>(means, fc1w, fc1b, fc2w, fc2b, s);
    final_kernel<<<2048, 256, 0, stream>>>(z, x, s, out);
}

// Round 4
// 589.286 us; speedup vs baseline: 1.7338x; 1.7338x over previous
//
#include <hip/hip_runtime.h>
#include <math.h>

#define BN_EPS 1e-5f

// ---------------------------------------------------------------------------
// Weight transpose: w[co][ci][kh][kw] -> wt[ci][kpos][co]
// so that for fixed (ci,kpos) the 8 per-co weights are contiguous (s_load).
// ---------------------------------------------------------------------------
__global__ void wtrans_kernel(const float* __restrict__ w, float* __restrict__ wt) {
    int i = blockIdx.x * 256 + threadIdx.x;
    if (i >= 128 * 128 * 9) return;
    int co = i / 1152;
    int rem = i - co * 1152;
    int ci = rem / 9;
    int kpos = rem - ci * 9;
    wt[ci * 1152 + kpos * 128 + co] = w[i];
}

// ---------------------------------------------------------------------------
// AdderNet conv (3x3, pad 1), PARTIAL over half the ci range.
// Grid: (4 row-tiles, 16 co-blocks of 8, 32 = 16 n x 2 ci-halves)
//       = 2048 blocks -> 8 blocks/CU -> 32 waves/CU (VGPR permitting).
// Block: 256 threads, 1 output pixel/thread, 8 output channels/thread.
// 4 ci planes staged per barrier (double-buffered, 10.9KB LDS).
// NO min-occupancy launch bound: r3 showed (256,8) forces VGPR=32 + massive
// scratch spills (458MB writes/dispatch). Natural allocation ~48-64 VGPR
// already permits 8 waves/SIMD.
// ---------------------------------------------------------------------------
__global__ __launch_bounds__(256) void adder_conv_part(
    const float* __restrict__ src,   // [16,128,32,32]
    const float* __restrict__ wt,    // [ci][9][co] transposed weights
    float* __restrict__ dst0, float* __restrict__ dst1) {
    const int t = threadIdx.x;
    const int r = t >> 5;                 // 0..7 row within tile
    const int c = t & 31;                 // 0..31 col
    const int row0 = blockIdx.x * 8;      // tile start row
    const int cb = blockIdx.y;            // co base = cb*8
    const int n = blockIdx.z & 15;
    const int half = blockIdx.z >> 4;     // ci half: 0 or 1
    const int cibase = half * 64;

    __shared__ float lds[2][4][340];      // 4 ci planes x (10x34), double-buffered

    // Staging geometry: element e -> (lr, lc) in padded tile, global offset.
    const int e0 = t;
    const int lr0 = e0 / 34, lc0 = e0 - lr0 * 34;
    const int gr0 = row0 + lr0 - 1, gc0 = lc0 - 1;
    const bool ok0 = (gr0 >= 0 && gr0 < 32 && gc0 >= 0 && gc0 < 32);
    const int off0 = gr0 * 32 + gc0;

    const int e1 = t + 256;
    const int lr1 = e1 / 34, lc1 = e1 - lr1 * 34;
    const int gr1 = row0 + lr1 - 1, gc1 = lc1 - 1;
    const bool st1 = (e1 < 340);
    const bool ok1 = st1 && (gr1 >= 0 && gr1 < 32 && gc1 >= 0 && gc1 < 32);
    const int off1 = gr1 * 32 + gc1;

    const float* splane = src + (size_t)n * (128 * 1024) + cibase * 1024;

    float acc[8];
#pragma unroll
    for (int j = 0; j < 8; ++j) acc[j] = 0.f;

    // Prologue: stage group 0 (4 planes) into buffer 0.
#pragma unroll
    for (int p = 0; p < 4; ++p) {
        const float* sp = splane + p * 1024;
        lds[0][p][e0] = ok0 ? sp[off0] : 0.f;
        if (st1) lds[0][p][e1] = ok1 ? sp[off1] : 0.f;
    }
    __syncthreads();

    const int base = r * 34 + c;
    int cur = 0;

    for (int g = 0; g < 16; ++g) {
        // Prefetch next group of 4 ci planes into registers (overlaps compute).
        float pf0[4], pf1[4];
        const bool more = (g < 15);
        if (more) {
#pragma unroll
            for (int p = 0; p < 4; ++p) {
                const float* sp = splane + ((g + 1) * 4 + p) * 1024;
                pf0[p] = ok0 ? sp[off0] : 0.f;
                pf1[p] = ok1 ? sp[off1] : 0.f;
            }
        }
        // Compute 4 ci planes.
#pragma unroll
        for (int p = 0; p < 4; ++p) {
            const int ci = cibase + g * 4 + p;
            const float* wrow = wt + ci * 1152 + cb * 8;   // wave-uniform
#pragma unroll
            for (int kh = 0; kh < 3; ++kh) {
#pragma unroll
                for (int kw = 0; kw < 3; ++kw) {
                    const float xv = lds[cur][p][base + kh * 34 + kw];
                    const float* wp = wrow + (kh * 3 + kw) * 128;
#pragma unroll
                    for (int j = 0; j < 8; ++j)
                        acc[j] += fabsf(xv - wp[j]);
                }
            }
        }
        if (more) {
#pragma unroll
            for (int p = 0; p < 4; ++p) {
                lds[cur ^ 1][p][e0] = pf0[p];
                if (st1) lds[cur ^ 1][p][e1] = pf1[p];
            }
        }
        __syncthreads();
        cur ^= 1;
    }

    // Epilogue: store positive partial sums, coalesced.
    float* dst = half ? dst1 : dst0;
#pragma unroll
    for (int j = 0; j < 8; ++j) {
        const int co = cb * 8 + j;
        dst[(((size_t)n * 128 + co) * 32 + (row0 + r)) * 32 + c] = acc[j];
    }
}

// ---------------------------------------------------------------------------
// Combine: out = BN(-(pA+pB)) (+ReLU). out may alias pA. float4 vectorized.
// ---------------------------------------------------------------------------
template <bool RELU>
__global__ void combine_bn(const float* pA, const float* pB,
                           const float* __restrict__ gamma, const float* __restrict__ beta,
                           const float* __restrict__ mean, const float* __restrict__ var,
                           float* out) {
    const int i = blockIdx.x * 256 + threadIdx.x;   // float4 index, 524288 total
    const int co = (i >> 8) & 127;                   // 256 float4 per (n,c)
    const float iv = gamma[co] * rsqrtf(var[co] + BN_EPS);
    const float bb = beta[co] - mean[co] * iv;
    const float4 a = ((const float4*)pA)[i];
    const float4 b = ((const float4*)pB)[i];
    float4 o;
    o.x = bb - (a.x + b.x) * iv;
    o.y = bb - (a.y + b.y) * iv;
    o.z = bb - (a.z + b.z) * iv;
    o.w = bb - (a.w + b.w) * iv;
    if (RELU) {
        o.x = fmaxf(o.x, 0.f); o.y = fmaxf(o.y, 0.f);
        o.z = fmaxf(o.z, 0.f); o.w = fmaxf(o.w, 0.f);
    }
    ((float4*)out)[i] = o;
}

// ---------------------------------------------------------------------------
// Per-(n,c) spatial mean of z: [16,128,32,32] -> [16,128]
// ---------------------------------------------------------------------------
__global__ void mean_kernel(const float* __restrict__ z, float* __restrict__ means) {
    const int b = blockIdx.x;  // n*128 + c
    const float4 v = ((const float4*)(z + (size_t)b * 1024))[threadIdx.x];
    float sum = v.x + v.y + v.z + v.w;
#pragma unroll
    for (int o = 32; o > 0; o >>= 1) sum += __shfl_down(sum, o);
    __shared__ float ws_[4];
    if ((threadIdx.x & 63) == 0) ws_[threadIdx.x >> 6] = sum;
    __syncthreads();
    if (threadIdx.x == 0)
        means[b] = (ws_[0] + ws_[1] + ws_[2] + ws_[3]) * (1.f / 1024.f);
}

// ---------------------------------------------------------------------------
// SE gate: s = sigmoid(fc2(relu(fc1(mean)+b1))+b2), per image n.
// ---------------------------------------------------------------------------
__global__ void se_kernel(const float* __restrict__ means,
                          const float* __restrict__ fc1w, const float* __restrict__ fc1b,
                          const float* __restrict__ fc2w, const float* __restrict__ fc2b,
                          float* __restrict__ s) {
    const int n = blockIdx.x;     // 16 blocks, 128 threads
    const int t = threadIdx.x;
    __shared__ float m[128], rr[8];
    m[t] = means[n * 128 + t];
    __syncthreads();
    if (t < 8) {
        float a = fc1b[t];
        for (int c2 = 0; c2 < 128; ++c2) a += fc1w[t * 128 + c2] * m[c2];
        rr[t] = fmaxf(a, 0.f);
    }
    __syncthreads();
    float a = fc2b[t];
#pragma unroll
    for (int j = 0; j < 8; ++j) a += fc2w[t * 8 + j] * rr[j];
    s[n * 128 + t] = 1.f / (1.f + expf(-a));
}

// ---------------------------------------------------------------------------
// Final: out = relu(z * s[n,c] + x), vectorized float4.
// ---------------------------------------------------------------------------
__global__ void final_kernel(const float* __restrict__ z, const float* __restrict__ x,
                             const float* __restrict__ s, float* __restrict__ out) {
    const int i = blockIdx.x * 256 + threadIdx.x;   // float4 index, 524288 total
    const int plane = i >> 8;                        // 256 float4 per (n,c)
    const float sc = s[plane];
    const float4 zv = ((const float4*)z)[i];
    const float4 xv = ((const float4*)x)[i];
    float4 o;
    o.x = fmaxf(zv.x * sc + xv.x, 0.f);
    o.y = fmaxf(zv.y * sc + xv.y, 0.f);
    o.z = fmaxf(zv.z * sc + xv.z, 0.f);
    o.w = fmaxf(zv.w * sc + xv.w, 0.f);
    ((float4*)out)[i] = o;
}

// ---------------------------------------------------------------------------
extern "C" void kernel_launch(void* const* d_in, const int* in_sizes, int n_in,
                              void* d_out, int out_size, void* d_ws, size_t ws_size,
                              hipStream_t stream) {
    const float* x    = (const float*)d_in[0];
    const float* w1   = (const float*)d_in[1];
    const float* g1   = (const float*)d_in[2];
    const float* b1   = (const float*)d_in[3];
    const float* m1   = (const float*)d_in[4];
    const float* v1   = (const float*)d_in[5];
    const float* w2   = (const float*)d_in[6];
    const float* g2   = (const float*)d_in[7];
    const float* b2   = (const float*)d_in[8];
    const float* m2   = (const float*)d_in[9];
    const float* v2   = (const float*)d_in[10];
    const float* fc1w = (const float*)d_in[11];
    const float* fc1b = (const float*)d_in[12];
    const float* fc2w = (const float*)d_in[13];
    const float* fc2b = (const float*)d_in[14];
    float* out = (float*)d_out;

    float* ws    = (float*)d_ws;
    float* wt1   = ws;                   // 147456
    float* wt2   = wt1 + 147456;         // 147456
    float* pA    = wt2 + 147456;         // 2097152
    float* pB    = pA + 2097152;         // 2097152
    float* z     = pB + 2097152;         // 2097152
    float* means = z + 2097152;          // 2048
    float* s     = means + 2048;         // 2048

    wtrans_kernel<<<576, 256, 0, stream>>>(w1, wt1);
    wtrans_kernel<<<576, 256, 0, stream>>>(w2, wt2);

    dim3 cgrid(4, 16, 32);
    // Conv1 partials -> pA (half0), pB (half1); combine -> y lives in pA.
    adder_conv_part<<<cgrid, 256, 0, stream>>>(x, wt1, pA, pB);
    combine_bn<true ><<<2048, 256, 0, stream>>>(pA, pB, g1, b1, m1, v1, pA);
    // Conv2 partials (src = y = pA) -> pB (half0), z (half1); combine -> z.
    adder_conv_part<<<cgrid, 256, 0, stream>>>(pA, wt2, pB, z);
    combine_bn<false><<<2048, 256, 0, stream>>>(pB, z, g2, b2, m2, v2, z);

    mean_kernel<<<2048, 256, 0, stream>>>(z, means);
    se_kernel<<<16, 128, 0, stream>>>(means, fc1w, fc1b, fc2w, fc2b, s);
    final_kernel<<<2048, 256, 0, stream>>>(z, x, s, out);
}